// Round 1
// baseline (2679.490 us; speedup 1.0000x reference)
//
#include <hip/hip_runtime.h>
#include <math.h>

#define N_NODES 50000
#define N_EDGES 800000
#define N_GRAPHS 512

// ---------------------------------------------------------------------------
// small utility kernels
// ---------------------------------------------------------------------------
__global__ void count_kernel(const int* __restrict__ idx, float* __restrict__ cnt, int n) {
    int i = blockIdx.x * blockDim.x + threadIdx.x;
    if (i < n) atomicAdd(&cnt[idx[i]], 1.0f);
}

__global__ void recip_max1_kernel(float* __restrict__ p, int n) {
    int i = blockIdx.x * blockDim.x + threadIdx.x;
    if (i < n) p[i] = 1.0f / fmaxf(p[i], 1.0f);
}

// ---------------------------------------------------------------------------
// edge scatter: agg[dst[e], :] += x[src[e], :]
// one thread per (edge, channel)
// ---------------------------------------------------------------------------
template<int D>
__global__ void scatter_add_kernel(const float* __restrict__ x,
                                   const int* __restrict__ src,
                                   const int* __restrict__ dst,
                                   float* __restrict__ agg) {
    int i = blockIdx.x * blockDim.x + threadIdx.x;
    if (i >= N_EDGES * D) return;
    int e = i / D;
    int d = i - e * D;
    atomicAdd(&agg[dst[e] * D + d], x[src[e] * D + d]);
}

// ---------------------------------------------------------------------------
// SAGE linear: Y = act( (agg * deginv) @ Wl^T + bl + X @ Wr^T )
// fp32 tiled GEMM, 64x64 tile, 256 threads, 4x4 acc each.
// MODE 0: leaky_relu(0.01), store
// MODE 1: relu, store
// MODE 2: relu, atomicAdd into pool[batch[n]*DOUT + o]  (fused global pool sum)
// ---------------------------------------------------------------------------
template<int DIN, int DOUT, int MODE>
__global__ __launch_bounds__(256) void sage_linear_kernel(
    const float* __restrict__ agg,     // N x DIN
    const float* __restrict__ xin,     // N x DIN
    const float* __restrict__ deginv,  // N
    const float* __restrict__ Wl,      // DOUT x DIN
    const float* __restrict__ Wr,      // DOUT x DIN
    const float* __restrict__ bias,    // DOUT
    float* __restrict__ out,           // N x DOUT, or pool (G x DOUT) for MODE 2
    const int* __restrict__ batch,     // N (MODE 2 only)
    int N)
{
    constexpr int BM = 64, BN = 64, BK = 16;
    __shared__ float As[BK][BM + 1];
    __shared__ float Bs[BK][BN + 1];

    const int bm = blockIdx.x * BM;
    const int bn = blockIdx.y * BN;
    const int tx = threadIdx.x % 16;
    const int ty = threadIdx.x / 16;

    float acc[4][4] = {};

    for (int pass = 0; pass < 2; ++pass) {
        const float* __restrict__ A = pass ? xin : agg;
        const float* __restrict__ B = pass ? Wr : Wl;
        for (int k0 = 0; k0 < DIN; k0 += BK) {
            // A tile: 64 rows (nodes) x 16 k
            for (int t = threadIdx.x; t < BM * BK; t += 256) {
                int r = t / BK, c = t % BK;
                int gr = bm + r, gc = k0 + c;
                float v = 0.0f;
                if (gr < N && gc < DIN) {
                    v = A[gr * DIN + gc];
                    if (pass == 0) v *= deginv[gr];
                }
                As[c][r] = v;
            }
            // B tile: 64 rows (out channels) x 16 k
            for (int t = threadIdx.x; t < BN * BK; t += 256) {
                int r = t / BK, c = t % BK;
                int gr = bn + r, gc = k0 + c;
                float v = (gc < DIN) ? B[gr * DIN + gc] : 0.0f;
                Bs[c][r] = v;
            }
            __syncthreads();
            #pragma unroll
            for (int kk = 0; kk < BK; ++kk) {
                float a[4], b[4];
                #pragma unroll
                for (int i = 0; i < 4; ++i) a[i] = As[kk][ty * 4 + i];
                #pragma unroll
                for (int j = 0; j < 4; ++j) b[j] = Bs[kk][tx * 4 + j];
                #pragma unroll
                for (int i = 0; i < 4; ++i)
                    #pragma unroll
                    for (int j = 0; j < 4; ++j)
                        acc[i][j] += a[i] * b[j];
            }
            __syncthreads();
        }
    }

    // epilogue
    #pragma unroll
    for (int i = 0; i < 4; ++i) {
        int n = bm + ty * 4 + i;
        if (n >= N) continue;
        #pragma unroll
        for (int j = 0; j < 4; ++j) {
            int o = bn + tx * 4 + j;
            float v = acc[i][j] + bias[o];
            if (MODE == 0) v = (v > 0.0f) ? v : 0.01f * v;
            else           v = fmaxf(v, 0.0f);
            if (MODE == 2) {
                atomicAdd(&out[batch[n] * DOUT + o], v);
            } else {
                out[n * DOUT + o] = v;
            }
        }
    }
}

// ---------------------------------------------------------------------------
// small dense layer over 512 graph rows: Y[g,:] = act(X[g,:]*scale[g] @ W^T + b)
// ACT 1: relu, ACT 2: sigmoid
// ---------------------------------------------------------------------------
template<int DIN, int DOUT, int ACT>
__global__ void dense_small_kernel(const float* __restrict__ X,
                                   const float* __restrict__ W,
                                   const float* __restrict__ b,
                                   const float* __restrict__ scale,  // per-row, may be null
                                   float* __restrict__ Y)
{
    __shared__ float xs[DIN];
    const int g = blockIdx.x;
    const float sc = scale ? scale[g] : 1.0f;
    for (int k = threadIdx.x; k < DIN; k += blockDim.x)
        xs[k] = X[g * DIN + k] * sc;
    __syncthreads();
    for (int o = threadIdx.x; o < DOUT; o += blockDim.x) {
        float s = b[o];
        #pragma unroll 4
        for (int k = 0; k < DIN; ++k) s += xs[k] * W[o * DIN + k];
        if (ACT == 1) s = fmaxf(s, 0.0f);
        if (ACT == 2) s = 1.0f / (1.0f + expf(-s));
        Y[g * DOUT + o] = s;
    }
}

// ---------------------------------------------------------------------------
extern "C" void kernel_launch(void* const* d_in, const int* in_sizes, int n_in,
                              void* d_out, int out_size, void* d_ws, size_t ws_size,
                              hipStream_t stream)
{
    const float* x     = (const float*)d_in[0];
    const int*   ei    = (const int*)  d_in[1];
    const int*   batch = (const int*)  d_in[2];
    const float* Wl1   = (const float*)d_in[3];
    const float* bl1   = (const float*)d_in[4];
    const float* Wr1   = (const float*)d_in[5];
    const float* Wl2   = (const float*)d_in[6];
    const float* bl2   = (const float*)d_in[7];
    const float* Wr2   = (const float*)d_in[8];
    const float* Wl3   = (const float*)d_in[9];
    const float* bl3   = (const float*)d_in[10];
    const float* Wr3   = (const float*)d_in[11];
    const float* Wf1   = (const float*)d_in[12];
    const float* bf1   = (const float*)d_in[13];
    const float* Wf2   = (const float*)d_in[14];
    const float* bf2   = (const float*)d_in[15];
    const float* Wo    = (const float*)d_in[16];
    const float* bo    = (const float*)d_in[17];

    const int* src = ei;            // edge_index[0]
    const int* dst = ei + N_EDGES;  // edge_index[1]

    // workspace layout (floats)
    float* ws = (float*)d_ws;
    size_t off = 0;
    float* deg  = ws + off; off += 50048;                 // deg -> deg_inv in place
    float* cnt  = ws + off; off += 512;                   // cnt -> inv_cnt in place
    float* pool = ws + off; off += (size_t)N_GRAPHS * 512;
    float* x4   = ws + off; off += (size_t)N_GRAPHS * 256;
    float* x5   = ws + off; off += (size_t)N_GRAPHS * 128;
    float* agg  = ws + off; off += (size_t)N_NODES * 256; // reused per layer
    float* x1   = ws + off; off += (size_t)N_NODES * 128;
    float* x2   = ws + off; off += (size_t)N_NODES * 256;

    // degrees and graph counts
    hipMemsetAsync(deg, 0, N_NODES * sizeof(float), stream);
    hipMemsetAsync(cnt, 0, N_GRAPHS * sizeof(float), stream);
    count_kernel<<<(N_EDGES + 255) / 256, 256, 0, stream>>>(dst, deg, N_EDGES);
    count_kernel<<<(N_NODES + 255) / 256, 256, 0, stream>>>(batch, cnt, N_NODES);
    recip_max1_kernel<<<(N_NODES + 255) / 256, 256, 0, stream>>>(deg, N_NODES);
    recip_max1_kernel<<<(N_GRAPHS + 255) / 256, 256, 0, stream>>>(cnt, N_GRAPHS);

    // ---- layer 1: 50 -> 128, leaky_relu ----
    hipMemsetAsync(agg, 0, (size_t)N_NODES * 50 * sizeof(float), stream);
    scatter_add_kernel<50><<<(N_EDGES * 50 + 255) / 256, 256, 0, stream>>>(x, src, dst, agg);
    {
        dim3 grid((N_NODES + 63) / 64, 128 / 64);
        sage_linear_kernel<50, 128, 0><<<grid, 256, 0, stream>>>(
            agg, x, deg, Wl1, Wr1, bl1, x1, nullptr, N_NODES);
    }

    // ---- layer 2: 128 -> 256, relu ----
    hipMemsetAsync(agg, 0, (size_t)N_NODES * 128 * sizeof(float), stream);
    scatter_add_kernel<128><<<(N_EDGES * 128 + 255) / 256, 256, 0, stream>>>(x1, src, dst, agg);
    {
        dim3 grid((N_NODES + 63) / 64, 256 / 64);
        sage_linear_kernel<128, 256, 1><<<grid, 256, 0, stream>>>(
            agg, x1, deg, Wl2, Wr2, bl2, x2, nullptr, N_NODES);
    }

    // ---- layer 3: 256 -> 512, relu, fused global-sum-pool ----
    hipMemsetAsync(pool, 0, (size_t)N_GRAPHS * 512 * sizeof(float), stream);
    hipMemsetAsync(agg, 0, (size_t)N_NODES * 256 * sizeof(float), stream);
    scatter_add_kernel<256><<<(N_EDGES * 256 + 255) / 256, 256, 0, stream>>>(x2, src, dst, agg);
    {
        dim3 grid((N_NODES + 63) / 64, 512 / 64);
        sage_linear_kernel<256, 512, 2><<<grid, 256, 0, stream>>>(
            agg, x2, deg, Wl3, Wr3, bl3, pool, batch, N_NODES);
    }

    // ---- MLP head over 512 graphs ----
    dense_small_kernel<512, 256, 1><<<N_GRAPHS, 256, 0, stream>>>(pool, Wf1, bf1, cnt, x4);
    dense_small_kernel<256, 128, 1><<<N_GRAPHS, 128, 0, stream>>>(x4, Wf2, bf2, nullptr, x5);
    dense_small_kernel<128, 1, 2><<<N_GRAPHS, 64, 0, stream>>>(x5, Wo, bo, nullptr, (float*)d_out);
}

// Round 2
// 655.966 us; speedup vs baseline: 4.0848x; 4.0848x over previous
//
#include <hip/hip_runtime.h>
#include <math.h>

#define N_NODES 50000
#define N_EDGES 800000
#define N_GRAPHS 512

typedef unsigned short u16;
typedef unsigned int u32;
using bf16x8 = __attribute__((ext_vector_type(8))) short;
using floatx4 = __attribute__((ext_vector_type(4))) float;

__device__ __forceinline__ float bf2f(u16 h) {
    union { u32 u; float f; } v; v.u = ((u32)h) << 16; return v.f;
}
__device__ __forceinline__ u16 f2bf(float f) {
    union { float f; u32 u; } v; v.f = f;
    u32 u = v.u;
    return (u16)((u + 0x7FFFu + ((u >> 16) & 1u)) >> 16);
}

// ---------------------------------------------------------------------------
// CSR build
// ---------------------------------------------------------------------------
__global__ void count_int_kernel(const int* __restrict__ idx, int* __restrict__ cnt, int n) {
    int i = blockIdx.x * blockDim.x + threadIdx.x;
    if (i < n) atomicAdd(&cnt[idx[i]], 1);
}

// exclusive scan of degi[0..N_NODES) into starts, 256-elem blocks
__global__ void scan1_kernel(const int* __restrict__ degi, int* __restrict__ starts,
                             int* __restrict__ bsum) {
    __shared__ int s[256];
    int t = threadIdx.x, i = blockIdx.x * 256 + t;
    int v = (i < N_NODES) ? degi[i] : 0;
    s[t] = v; __syncthreads();
    for (int off = 1; off < 256; off <<= 1) {
        int x = (t >= off) ? s[t - off] : 0;
        __syncthreads();
        s[t] += x;
        __syncthreads();
    }
    if (i < N_NODES) starts[i] = s[t] - v;   // exclusive, block-local
    if (t == 255) bsum[blockIdx.x] = s[255];
}

__global__ void scan2_kernel(const int* __restrict__ bsum, int* __restrict__ boff,
                             int* __restrict__ starts, int nb) {
    int acc = 0;
    for (int b = 0; b < nb; ++b) { boff[b] = acc; acc += bsum[b]; }
    starts[N_NODES] = acc;
}

__global__ void scan3_kernel(int* __restrict__ starts, const int* __restrict__ boff) {
    int i = blockIdx.x * 256 + threadIdx.x;
    if (i < N_NODES) starts[i] += boff[blockIdx.x];
}

__global__ void fill_csr_kernel(const int* __restrict__ src, const int* __restrict__ dst,
                                const int* __restrict__ starts, int* __restrict__ cursor,
                                int* __restrict__ csr) {
    int e = blockIdx.x * blockDim.x + threadIdx.x;
    if (e >= N_EDGES) return;
    int d = dst[e];
    int p = atomicAdd(&cursor[d], 1);
    csr[starts[d] + p] = src[e];
}

// graph starts from sorted batch
__global__ void gstart_kernel(const int* __restrict__ batch, int* __restrict__ gstart) {
    int i = blockIdx.x * blockDim.x + threadIdx.x;
    if (i >= N_NODES) return;
    int b = batch[i];
    int bp = (i == 0) ? -1 : batch[i - 1];
    for (int g = bp + 1; g <= b; ++g) gstart[g] = i;
    if (i == N_NODES - 1)
        for (int g = b + 1; g <= N_GRAPHS; ++g) gstart[g] = N_NODES;
}

__global__ void cntinv_kernel(const int* __restrict__ gstart, float* __restrict__ cntinv) {
    int g = blockIdx.x * blockDim.x + threadIdx.x;
    if (g < N_GRAPHS) cntinv[g] = 1.0f / fmaxf((float)(gstart[g + 1] - gstart[g]), 1.0f);
}

// ---------------------------------------------------------------------------
// input / weight conversion to bf16 (with zero padding)
// abuf layout per node: [agg (DINP cols) | x (DINP cols)], stride 2*DINP
// ---------------------------------------------------------------------------
__global__ void conv_x_kernel(const float* __restrict__ x, u16* __restrict__ abuf1) {
    int i = blockIdx.x * blockDim.x + threadIdx.x;
    if (i >= N_NODES * 64) return;
    int n = i >> 6, c = i & 63;
    float v = (c < 50) ? x[n * 50 + c] : 0.0f;
    abuf1[(size_t)n * 128 + 64 + c] = f2bf(v);
}

template<int DIN, int DINP, int DOUT>
__global__ void conv_w_kernel(const float* __restrict__ Wl, const float* __restrict__ Wr,
                              u16* __restrict__ wbuf) {
    int i = blockIdx.x * blockDim.x + threadIdx.x;
    if (i >= DOUT * DINP) return;
    int o = i / DINP, c = i % DINP;
    float vl = (c < DIN) ? Wl[o * DIN + c] : 0.0f;
    float vr = (c < DIN) ? Wr[o * DIN + c] : 0.0f;
    wbuf[(size_t)o * 2 * DINP + c] = f2bf(vl);
    wbuf[(size_t)o * 2 * DINP + DINP + c] = f2bf(vr);
}

// ---------------------------------------------------------------------------
// CSR gather aggregation: abuf[n][0..DINP) = mean over in-neighbors of
// abuf[src][DINP..2*DINP).  One wave per node, fp32 accumulate.
// ---------------------------------------------------------------------------
template<int DINP>
__global__ __launch_bounds__(256) void csr_agg_kernel(const int* __restrict__ starts,
                                                      const int* __restrict__ csr,
                                                      u16* __restrict__ abuf) {
    constexpr int STRIDE = 2 * DINP;
    constexpr int C = DINP / 64;
    int wave = threadIdx.x >> 6, lane = threadIdx.x & 63;
    int n = blockIdx.x * 4 + wave;
    if (n >= N_NODES) return;
    int s0 = starts[n], s1 = starts[n + 1];
    float acc[C];
    #pragma unroll
    for (int c = 0; c < C; ++c) acc[c] = 0.0f;
    const u16* xin = abuf + DINP;
    for (int e = s0; e < s1; ++e) {
        int sidx = csr[e];
        const u16* p = xin + (size_t)sidx * STRIDE + lane * C;
        if constexpr (C == 1) {
            acc[0] += bf2f(p[0]);
        } else if constexpr (C == 2) {
            ushort2 u = *(const ushort2*)p;
            acc[0] += bf2f(u.x); acc[1] += bf2f(u.y);
        } else {
            ushort4 u = *(const ushort4*)p;
            acc[0] += bf2f(u.x); acc[1] += bf2f(u.y);
            acc[2] += bf2f(u.z); acc[3] += bf2f(u.w);
        }
    }
    float sc = 1.0f / fmaxf((float)(s1 - s0), 1.0f);
    u16* o = abuf + (size_t)n * STRIDE + lane * C;
    #pragma unroll
    for (int c = 0; c < C; ++c) o[c] = f2bf(acc[c] * sc);
}

// ---------------------------------------------------------------------------
// bf16 MFMA GEMM: out = act( A(Nx K) @ W(DOUT x K)^T + bias )
// 128x128 tile, 4 waves (2x2), each wave 64x64 via 4x4 mfma_16x16x32.
// ACT 0: leaky_relu(0.01); 1: relu.
// MODE 0: store bf16 at out[node*outStride + outOff + o]
// MODE 1: relu + atomicAdd into pool[batch[node]*512 + o] (global pool sum)
// ---------------------------------------------------------------------------
template<int K, int DOUT, int ACT, int MODE>
__global__ __launch_bounds__(256) void gemm_bf16_kernel(
    const u16* __restrict__ A, const u16* __restrict__ W,
    const float* __restrict__ bias,
    u16* __restrict__ out, int outStride, int outOff,
    float* __restrict__ pool, const int* __restrict__ batch, int N)
{
    constexpr int BM = 128, BN = 128;
    constexpr int LDA = 40;  // row pitch in bf16 elems for a 32-elem k-slab (bank decorrelation)
    __shared__ u16 As[BM * LDA];
    __shared__ u16 Bs[BN * LDA];

    const int bm = blockIdx.x * BM;
    const int bn = blockIdx.y * BN;
    const int tid = threadIdx.x;
    const int wave = tid >> 6, lane = tid & 63;
    const int wm = (wave & 1) * 64, wn = (wave >> 1) * 64;
    const int lm = lane & 15, lq = lane >> 4;

    floatx4 acc[4][4] = {};

    for (int k0 = 0; k0 < K; k0 += 32) {
        #pragma unroll
        for (int it = 0; it < 2; ++it) {
            int t = tid + it * 256;          // 0..511
            int r = t >> 2;                  // 0..127
            int c = (t & 3) * 8;             // 0,8,16,24
            int node = bm + r;
            uint4 va = make_uint4(0u, 0u, 0u, 0u);
            if (node < N) va = *(const uint4*)(A + (size_t)node * K + k0 + c);
            *(uint4*)&As[r * LDA + c] = va;
            uint4 vb = *(const uint4*)(W + (size_t)(bn + r) * K + k0 + c);
            *(uint4*)&Bs[r * LDA + c] = vb;
        }
        __syncthreads();

        bf16x8 af[4], bfr[4];
        #pragma unroll
        for (int mi = 0; mi < 4; ++mi)
            af[mi] = *(const bf16x8*)&As[(wm + mi * 16 + lm) * LDA + lq * 8];
        #pragma unroll
        for (int ni = 0; ni < 4; ++ni)
            bfr[ni] = *(const bf16x8*)&Bs[(wn + ni * 16 + lm) * LDA + lq * 8];
        #pragma unroll
        for (int mi = 0; mi < 4; ++mi)
            #pragma unroll
            for (int ni = 0; ni < 4; ++ni)
                acc[mi][ni] = __builtin_amdgcn_mfma_f32_16x16x32_bf16(
                    af[mi], bfr[ni], acc[mi][ni], 0, 0, 0);
        __syncthreads();
    }

    // epilogue: D[row=node][col=o], node = base + lq*4 + r, o = base + lm
    #pragma unroll
    for (int mi = 0; mi < 4; ++mi) {
        int node0 = bm + wm + mi * 16 + lq * 4;
        int b0 = -1, b3 = -2;
        if (MODE == 1) {
            b0 = (node0 < N) ? batch[node0] : -1;
            b3 = (node0 + 3 < N) ? batch[node0 + 3] : -2;
        }
        #pragma unroll
        for (int ni = 0; ni < 4; ++ni) {
            int o = bn + wn + ni * 16 + lm;
            float bi = bias[o];
            if (MODE == 0) {
                #pragma unroll
                for (int r = 0; r < 4; ++r) {
                    int node = node0 + r;
                    if (node >= N) continue;
                    float v = acc[mi][ni][r] + bi;
                    if (ACT == 0) v = (v > 0.0f) ? v : 0.01f * v;
                    else          v = fmaxf(v, 0.0f);
                    out[(size_t)node * outStride + outOff + o] = f2bf(v);
                }
            } else {
                float v[4];
                #pragma unroll
                for (int r = 0; r < 4; ++r)
                    v[r] = (node0 + r < N) ? fmaxf(acc[mi][ni][r] + bi, 0.0f) : 0.0f;
                if (b0 == b3) {
                    atomicAdd(&pool[(size_t)b0 * 512 + o], v[0] + v[1] + v[2] + v[3]);
                } else {
                    for (int r = 0; r < 4; ++r)
                        if (node0 + r < N)
                            atomicAdd(&pool[(size_t)batch[node0 + r] * 512 + o], v[r]);
                }
            }
        }
    }
}

// ---------------------------------------------------------------------------
// small dense layer over 512 graph rows (fp32 head)
// ---------------------------------------------------------------------------
template<int DIN, int DOUT, int ACT>
__global__ void dense_small_kernel(const float* __restrict__ X,
                                   const float* __restrict__ W,
                                   const float* __restrict__ b,
                                   const float* __restrict__ scale,
                                   float* __restrict__ Y)
{
    __shared__ float xs[DIN];
    const int g = blockIdx.x;
    const float sc = scale ? scale[g] : 1.0f;
    for (int k = threadIdx.x; k < DIN; k += blockDim.x)
        xs[k] = X[g * DIN + k] * sc;
    __syncthreads();
    for (int o = threadIdx.x; o < DOUT; o += blockDim.x) {
        float s = b[o];
        #pragma unroll 4
        for (int k = 0; k < DIN; ++k) s += xs[k] * W[o * DIN + k];
        if (ACT == 1) s = fmaxf(s, 0.0f);
        if (ACT == 2) s = 1.0f / (1.0f + expf(-s));
        Y[g * DOUT + o] = s;
    }
}

// ---------------------------------------------------------------------------
extern "C" void kernel_launch(void* const* d_in, const int* in_sizes, int n_in,
                              void* d_out, int out_size, void* d_ws, size_t ws_size,
                              hipStream_t stream)
{
    const float* x     = (const float*)d_in[0];
    const int*   ei    = (const int*)  d_in[1];
    const int*   batch = (const int*)  d_in[2];
    const float* Wl1   = (const float*)d_in[3];
    const float* bl1   = (const float*)d_in[4];
    const float* Wr1   = (const float*)d_in[5];
    const float* Wl2   = (const float*)d_in[6];
    const float* bl2   = (const float*)d_in[7];
    const float* Wr2   = (const float*)d_in[8];
    const float* Wl3   = (const float*)d_in[9];
    const float* bl3   = (const float*)d_in[10];
    const float* Wr3   = (const float*)d_in[11];
    const float* Wf1   = (const float*)d_in[12];
    const float* bf1   = (const float*)d_in[13];
    const float* Wf2   = (const float*)d_in[14];
    const float* bf2   = (const float*)d_in[15];
    const float* Wo    = (const float*)d_in[16];
    const float* bo    = (const float*)d_in[17];

    const int* src = ei;
    const int* dst = ei + N_EDGES;

    // workspace layout
    char* p = (char*)d_ws;
    auto alloc = [&](size_t bytes) { char* r = p; p += (bytes + 255) & ~(size_t)255; return r; };
    int*   degi   = (int*)  alloc(50176 * 4);
    int*   starts = (int*)  alloc(50432 * 4);   // N_NODES+1
    int*   bsum   = (int*)  alloc(256 * 4);
    int*   boff   = (int*)  alloc(256 * 4);
    int*   cursor = (int*)  alloc(50176 * 4);
    int*   csr    = (int*)  alloc((size_t)N_EDGES * 4);
    int*   gstart = (int*)  alloc(513 * 4);
    float* cntinv = (float*)alloc(512 * 4);
    float* pool   = (float*)alloc((size_t)512 * 512 * 4);
    float* x4     = (float*)alloc((size_t)512 * 256 * 4);
    float* x5     = (float*)alloc((size_t)512 * 128 * 4);
    u16*   abuf1  = (u16*)  alloc((size_t)N_NODES * 128 * 2);
    u16*   abuf2  = (u16*)  alloc((size_t)N_NODES * 256 * 2);
    u16*   abuf3  = (u16*)  alloc((size_t)N_NODES * 512 * 2);
    u16*   wb1    = (u16*)  alloc((size_t)128 * 128 * 2);
    u16*   wb2    = (u16*)  alloc((size_t)256 * 256 * 2);
    u16*   wb3    = (u16*)  alloc((size_t)512 * 512 * 2);

    // ---- CSR build ----
    hipMemsetAsync(degi, 0, 50176 * 4, stream);
    hipMemsetAsync(cursor, 0, 50176 * 4, stream);
    count_int_kernel<<<(N_EDGES + 255) / 256, 256, 0, stream>>>(dst, degi, N_EDGES);
    scan1_kernel<<<196, 256, 0, stream>>>(degi, starts, bsum);
    scan2_kernel<<<1, 1, 0, stream>>>(bsum, boff, starts, 196);
    scan3_kernel<<<196, 256, 0, stream>>>(starts, boff);
    fill_csr_kernel<<<(N_EDGES + 255) / 256, 256, 0, stream>>>(src, dst, starts, cursor, csr);
    gstart_kernel<<<196, 256, 0, stream>>>(batch, gstart);
    cntinv_kernel<<<2, 256, 0, stream>>>(gstart, cntinv);

    // ---- convert inputs / weights to bf16 ----
    conv_x_kernel<<<(N_NODES * 64 + 255) / 256, 256, 0, stream>>>(x, abuf1);
    conv_w_kernel<50, 64, 128><<<(128 * 64 + 255) / 256, 256, 0, stream>>>(Wl1, Wr1, wb1);
    conv_w_kernel<128, 128, 256><<<(256 * 128 + 255) / 256, 256, 0, stream>>>(Wl2, Wr2, wb2);
    conv_w_kernel<256, 256, 512><<<(512 * 256 + 255) / 256, 256, 0, stream>>>(Wl3, Wr3, wb3);

    const int GB = 12500;   // node blocks for aggregation (4 waves/block)
    const int MB = (N_NODES + 127) / 128;

    // ---- layer 1: 50 -> 128, leaky_relu ----
    csr_agg_kernel<64><<<GB, 256, 0, stream>>>(starts, csr, abuf1);
    {
        dim3 grid(MB, 1);
        gemm_bf16_kernel<128, 128, 0, 0><<<grid, 256, 0, stream>>>(
            abuf1, wb1, bl1, abuf2, 256, 128, nullptr, nullptr, N_NODES);
    }

    // ---- layer 2: 128 -> 256, relu ----
    csr_agg_kernel<128><<<GB, 256, 0, stream>>>(starts, csr, abuf2);
    {
        dim3 grid(MB, 2);
        gemm_bf16_kernel<256, 256, 1, 0><<<grid, 256, 0, stream>>>(
            abuf2, wb2, bl2, abuf3, 512, 256, nullptr, nullptr, N_NODES);
    }

    // ---- layer 3: 256 -> 512, relu + fused pool sum ----
    csr_agg_kernel<256><<<GB, 256, 0, stream>>>(starts, csr, abuf3);
    hipMemsetAsync(pool, 0, (size_t)512 * 512 * 4, stream);
    {
        dim3 grid(MB, 4);
        gemm_bf16_kernel<512, 512, 1, 1><<<grid, 256, 0, stream>>>(
            abuf3, wb3, bl3, nullptr, 0, 0, pool, batch, N_NODES);
    }

    // ---- MLP head (fp32) ----
    dense_small_kernel<512, 256, 1><<<N_GRAPHS, 256, 0, stream>>>(pool, Wf1, bf1, cntinv, x4);
    dense_small_kernel<256, 128, 1><<<N_GRAPHS, 128, 0, stream>>>(x4, Wf2, bf2, nullptr, x5);
    dense_small_kernel<128, 1, 2><<<N_GRAPHS, 64, 0, stream>>>(x5, Wo, bo, nullptr, (float*)d_out);
}

// Round 3
// 518.421 us; speedup vs baseline: 5.1686x; 1.2653x over previous
//
#include <hip/hip_runtime.h>
#include <math.h>

#define N_NODES 50000
#define N_EDGES 800000
#define N_GRAPHS 512
#define M_PAD 50048   // N_NODES rounded up to 128

typedef unsigned short u16;
typedef unsigned int u32;
using bf16x8 = __attribute__((ext_vector_type(8))) short;
using floatx4 = __attribute__((ext_vector_type(4))) float;

__device__ __forceinline__ float bf2f(u16 h) {
    union { u32 u; float f; } v; v.u = ((u32)h) << 16; return v.f;
}
__device__ __forceinline__ u16 f2bf(float f) {
    union { float f; u32 u; } v; v.f = f;
    u32 u = v.u;
    return (u16)((u + 0x7FFFu + ((u >> 16) & 1u)) >> 16);
}

// async global->LDS, 16 B per lane; LDS dest = base + lane*16 (wave-uniform base)
__device__ __forceinline__ void load_lds16(const u16* g, u16* l) {
    __builtin_amdgcn_global_load_lds(
        (const __attribute__((address_space(1))) u32*)g,
        (__attribute__((address_space(3))) u32*)l, 16, 0, 0);
}

// ---------------------------------------------------------------------------
// CSR build
// ---------------------------------------------------------------------------
__global__ void count_int_kernel(const int* __restrict__ idx, int* __restrict__ cnt, int n) {
    int i = blockIdx.x * blockDim.x + threadIdx.x;
    if (i < n) atomicAdd(&cnt[idx[i]], 1);
}

__global__ void scan1_kernel(const int* __restrict__ degi, int* __restrict__ starts,
                             int* __restrict__ bsum) {
    __shared__ int s[256];
    int t = threadIdx.x, i = blockIdx.x * 256 + t;
    int v = (i < N_NODES) ? degi[i] : 0;
    s[t] = v; __syncthreads();
    for (int off = 1; off < 256; off <<= 1) {
        int x = (t >= off) ? s[t - off] : 0;
        __syncthreads();
        s[t] += x;
        __syncthreads();
    }
    if (i < N_NODES) starts[i] = s[t] - v;
    if (t == 255) bsum[blockIdx.x] = s[255];
}

// parallel block-level scan of bsum (nb<=256) -> boff
__global__ void scan2_kernel(const int* __restrict__ bsum, int* __restrict__ boff,
                             int* __restrict__ starts, int nb) {
    __shared__ int s[256];
    int t = threadIdx.x;
    int v = (t < nb) ? bsum[t] : 0;
    s[t] = v; __syncthreads();
    for (int off = 1; off < 256; off <<= 1) {
        int x = (t >= off) ? s[t - off] : 0;
        __syncthreads();
        s[t] += x;
        __syncthreads();
    }
    if (t < nb) boff[t] = s[t] - v;
    if (t == nb - 1) starts[N_NODES] = s[t];
}

__global__ void scan3_kernel(int* __restrict__ starts, const int* __restrict__ boff) {
    int i = blockIdx.x * 256 + threadIdx.x;
    if (i < N_NODES) starts[i] += boff[blockIdx.x];
}

__global__ void fill_csr_kernel(const int* __restrict__ src, const int* __restrict__ dst,
                                const int* __restrict__ starts, int* __restrict__ cursor,
                                int* __restrict__ csr) {
    int e = blockIdx.x * blockDim.x + threadIdx.x;
    if (e >= N_EDGES) return;
    int d = dst[e];
    int p = atomicAdd(&cursor[d], 1);
    csr[starts[d] + p] = src[e];
}

__global__ void gstart_kernel(const int* __restrict__ batch, int* __restrict__ gstart) {
    int i = blockIdx.x * blockDim.x + threadIdx.x;
    if (i >= N_NODES) return;
    int b = batch[i];
    int bp = (i == 0) ? -1 : batch[i - 1];
    for (int g = bp + 1; g <= b; ++g) gstart[g] = i;
    if (i == N_NODES - 1)
        for (int g = b + 1; g <= N_GRAPHS; ++g) gstart[g] = N_NODES;
}

__global__ void cntinv_kernel(const int* __restrict__ gstart, float* __restrict__ cntinv) {
    int g = blockIdx.x * blockDim.x + threadIdx.x;
    if (g < N_GRAPHS) cntinv[g] = 1.0f / fmaxf((float)(gstart[g + 1] - gstart[g]), 1.0f);
}

// ---------------------------------------------------------------------------
// conversions
// ---------------------------------------------------------------------------
__global__ void conv_x_kernel(const float* __restrict__ x, u16* __restrict__ abuf1) {
    int i = blockIdx.x * blockDim.x + threadIdx.x;
    if (i >= N_NODES * 64) return;
    int n = i >> 6, c = i & 63;
    float v = (c < 50) ? x[n * 50 + c] : 0.0f;
    abuf1[(size_t)n * 128 + 64 + c] = f2bf(v);
}

template<int DIN, int DINP, int DOUT>
__global__ void conv_w_kernel(const float* __restrict__ Wl, const float* __restrict__ Wr,
                              u16* __restrict__ wbuf) {
    int i = blockIdx.x * blockDim.x + threadIdx.x;
    if (i >= DOUT * DINP) return;
    int o = i / DINP, c = i % DINP;
    float vl = (c < DIN) ? Wl[o * DIN + c] : 0.0f;
    float vr = (c < DIN) ? Wr[o * DIN + c] : 0.0f;
    wbuf[(size_t)o * 2 * DINP + c] = f2bf(vl);
    wbuf[(size_t)o * 2 * DINP + DINP + c] = f2bf(vr);
}

// ---------------------------------------------------------------------------
// CSR gather mean-aggregation, one wave per node, unroll-4 edge prefetch
// ---------------------------------------------------------------------------
template<int DINP>
__global__ __launch_bounds__(256) void csr_agg_kernel(const int* __restrict__ starts,
                                                      const int* __restrict__ csr,
                                                      u16* __restrict__ abuf) {
    constexpr int STRIDE = 2 * DINP;
    constexpr int C = (DINP >= 256) ? 4 : (DINP >= 128 ? 2 : 1);
    int wave = threadIdx.x >> 6, lane = threadIdx.x & 63;
    int n = blockIdx.x * 4 + wave;
    if (n >= N_NODES) return;
    int s0 = starts[n], s1 = starts[n + 1];
    float acc[C];
    #pragma unroll
    for (int c = 0; c < C; ++c) acc[c] = 0.0f;
    const u16* xin = abuf + DINP;

    auto accum = [&](int sidx) {
        const u16* p = xin + (size_t)sidx * STRIDE + lane * C;
        if constexpr (C == 1) {
            acc[0] += bf2f(p[0]);
        } else if constexpr (C == 2) {
            ushort2 u = *(const ushort2*)p;
            acc[0] += bf2f(u.x); acc[1] += bf2f(u.y);
        } else {
            ushort4 u = *(const ushort4*)p;
            acc[0] += bf2f(u.x); acc[1] += bf2f(u.y);
            acc[2] += bf2f(u.z); acc[3] += bf2f(u.w);
        }
    };

    int e = s0;
    for (; e + 4 <= s1; e += 4) {
        int i0 = csr[e], i1 = csr[e + 1], i2 = csr[e + 2], i3 = csr[e + 3];
        accum(i0); accum(i1); accum(i2); accum(i3);
    }
    for (; e < s1; ++e) accum(csr[e]);

    float sc = 1.0f / fmaxf((float)(s1 - s0), 1.0f);
    u16* o = abuf + (size_t)n * STRIDE + lane * C;
    #pragma unroll
    for (int c = 0; c < C; ++c) o[c] = f2bf(acc[c] * sc);
}

// ---------------------------------------------------------------------------
// bf16 MFMA GEMM, m97-style: global_load_lds(16B) staging, contiguous 128x32
// k-slab in LDS, BK=32, 128x128 tile, 4 waves 2x2, 4x4 mfma_16x16x32 each.
// Grid: 1D, n-fastest (blocks sharing an A-tile are adjacent).
// A must have M_PAD rows (garbage rows beyond N are masked at the epilogue).
// ACT 0: leaky_relu, 1: relu.  MODE 0: store bf16.  MODE 1: pool atomicAdd.
// ---------------------------------------------------------------------------
template<int K, int NB, int ACT, int MODE>
__global__ __launch_bounds__(256) void gemm_bf16_kernel(
    const u16* __restrict__ A, const u16* __restrict__ W,
    const float* __restrict__ bias,
    u16* __restrict__ out, int outStride, int outOff,
    float* __restrict__ pool, const int* __restrict__ batch, int N)
{
    __shared__ u16 As[128 * 32];
    __shared__ u16 Bs[128 * 32];

    const int bx = blockIdx.x;
    const int bm = (bx / NB) * 128;
    const int bn = (bx % NB) * 128;
    const int tid = threadIdx.x;
    const int wave = tid >> 6, lane = tid & 63;
    const int wm = (wave & 1) * 64, wn = (wave >> 1) * 64;
    const int lm = lane & 15, lq = lane >> 4;

    // staging addresses: wave w covers rows w*32..w*32+31 (two 16-row issues)
    const int srow = wave * 32 + (lane >> 2);   // +0 and +16
    const int scol = (lane & 3) * 8;            // u16 elems within 32-elem slab
    const u16* ga0 = A + (size_t)(bm + srow) * K + scol;
    const u16* ga1 = A + (size_t)(bm + srow + 16) * K + scol;
    const u16* gb0 = W + (size_t)(bn + srow) * K + scol;
    const u16* gb1 = W + (size_t)(bn + srow + 16) * K + scol;
    u16* la0 = &As[(wave * 32) * 32];
    u16* la1 = &As[(wave * 32 + 16) * 32];
    u16* lb0 = &Bs[(wave * 32) * 32];
    u16* lb1 = &Bs[(wave * 32 + 16) * 32];

    floatx4 acc[4][4] = {};

    for (int k0 = 0; k0 < K; k0 += 32) {
        load_lds16(ga0 + k0, la0);
        load_lds16(ga1 + k0, la1);
        load_lds16(gb0 + k0, lb0);
        load_lds16(gb1 + k0, lb1);
        __syncthreads();

        bf16x8 af[4], bfr[4];
        #pragma unroll
        for (int mi = 0; mi < 4; ++mi)
            af[mi] = *(const bf16x8*)&As[(wm + mi * 16 + lm) * 32 + lq * 8];
        #pragma unroll
        for (int ni = 0; ni < 4; ++ni)
            bfr[ni] = *(const bf16x8*)&Bs[(wn + ni * 16 + lm) * 32 + lq * 8];
        #pragma unroll
        for (int mi = 0; mi < 4; ++mi)
            #pragma unroll
            for (int ni = 0; ni < 4; ++ni)
                acc[mi][ni] = __builtin_amdgcn_mfma_f32_16x16x32_bf16(
                    af[mi], bfr[ni], acc[mi][ni], 0, 0, 0);
        __syncthreads();
    }

    // epilogue: D row=node (bm+wm+mi*16+lq*4+r), col=o (bn+wn+ni*16+lm)
    #pragma unroll
    for (int mi = 0; mi < 4; ++mi) {
        int node0 = bm + wm + mi * 16 + lq * 4;
        int b0 = -1, b3 = -2;
        if (MODE == 1) {
            b0 = (node0 < N) ? batch[node0] : -1;
            b3 = (node0 + 3 < N) ? batch[node0 + 3] : -2;
        }
        #pragma unroll
        for (int ni = 0; ni < 4; ++ni) {
            int o = bn + wn + ni * 16 + lm;
            float bi = bias[o];
            if (MODE == 0) {
                #pragma unroll
                for (int r = 0; r < 4; ++r) {
                    int node = node0 + r;
                    if (node >= N) continue;
                    float v = acc[mi][ni][r] + bi;
                    if (ACT == 0) v = (v > 0.0f) ? v : 0.01f * v;
                    else          v = fmaxf(v, 0.0f);
                    out[(size_t)node * outStride + outOff + o] = f2bf(v);
                }
            } else {
                float v[4];
                #pragma unroll
                for (int r = 0; r < 4; ++r)
                    v[r] = (node0 + r < N) ? fmaxf(acc[mi][ni][r] + bi, 0.0f) : 0.0f;
                if (b0 == b3) {
                    atomicAdd(&pool[(size_t)b0 * 512 + o], v[0] + v[1] + v[2] + v[3]);
                } else {
                    for (int r = 0; r < 4; ++r)
                        if (node0 + r < N)
                            atomicAdd(&pool[(size_t)batch[node0 + r] * 512 + o], v[r]);
                }
            }
        }
    }
}

// ---------------------------------------------------------------------------
// small dense layers over 512 graph rows (fp32 head)
// ---------------------------------------------------------------------------
template<int DIN, int DOUT, int ACT>
__global__ void dense_small_kernel(const float* __restrict__ X,
                                   const float* __restrict__ W,
                                   const float* __restrict__ b,
                                   const float* __restrict__ scale,
                                   float* __restrict__ Y)
{
    __shared__ float xs[DIN];
    const int g = blockIdx.x;
    const float sc = scale ? scale[g] : 1.0f;
    for (int k = threadIdx.x; k < DIN; k += blockDim.x)
        xs[k] = X[g * DIN + k] * sc;
    __syncthreads();
    for (int o = threadIdx.x; o < DOUT; o += blockDim.x) {
        float s = b[o];
        #pragma unroll 4
        for (int k = 0; k < DIN; ++k) s += xs[k] * W[o * DIN + k];
        if (ACT == 1) s = fmaxf(s, 0.0f);
        if (ACT == 2) s = 1.0f / (1.0f + expf(-s));
        Y[g * DOUT + o] = s;
    }
}

// ---------------------------------------------------------------------------
extern "C" void kernel_launch(void* const* d_in, const int* in_sizes, int n_in,
                              void* d_out, int out_size, void* d_ws, size_t ws_size,
                              hipStream_t stream)
{
    const float* x     = (const float*)d_in[0];
    const int*   ei    = (const int*)  d_in[1];
    const int*   batch = (const int*)  d_in[2];
    const float* Wl1   = (const float*)d_in[3];
    const float* bl1   = (const float*)d_in[4];
    const float* Wr1   = (const float*)d_in[5];
    const float* Wl2   = (const float*)d_in[6];
    const float* bl2   = (const float*)d_in[7];
    const float* Wr2   = (const float*)d_in[8];
    const float* Wl3   = (const float*)d_in[9];
    const float* bl3   = (const float*)d_in[10];
    const float* Wr3   = (const float*)d_in[11];
    const float* Wf1   = (const float*)d_in[12];
    const float* bf1   = (const float*)d_in[13];
    const float* Wf2   = (const float*)d_in[14];
    const float* bf2   = (const float*)d_in[15];
    const float* Wo    = (const float*)d_in[16];
    const float* bo    = (const float*)d_in[17];

    const int* src = ei;
    const int* dst = ei + N_EDGES;

    char* p = (char*)d_ws;
    auto alloc = [&](size_t bytes) { char* r = p; p += (bytes + 255) & ~(size_t)255; return r; };
    int*   degi   = (int*)  alloc(50176 * 4);
    int*   starts = (int*)  alloc(50432 * 4);
    int*   bsum   = (int*)  alloc(256 * 4);
    int*   boff   = (int*)  alloc(256 * 4);
    int*   cursor = (int*)  alloc(50176 * 4);
    int*   csr    = (int*)  alloc((size_t)N_EDGES * 4);
    int*   gstart = (int*)  alloc(513 * 4);
    float* cntinv = (float*)alloc(512 * 4);
    float* pool   = (float*)alloc((size_t)512 * 512 * 4);
    float* x4     = (float*)alloc((size_t)512 * 256 * 4);
    float* x5     = (float*)alloc((size_t)512 * 128 * 4);
    u16*   abuf1  = (u16*)  alloc((size_t)M_PAD * 128 * 2);
    u16*   abuf2  = (u16*)  alloc((size_t)M_PAD * 256 * 2);
    u16*   abuf3  = (u16*)  alloc((size_t)M_PAD * 512 * 2);
    u16*   wb1    = (u16*)  alloc((size_t)128 * 128 * 2);
    u16*   wb2    = (u16*)  alloc((size_t)256 * 256 * 2);
    u16*   wb3    = (u16*)  alloc((size_t)512 * 512 * 2);

    // ---- CSR build ----
    hipMemsetAsync(degi, 0, 50176 * 4, stream);
    hipMemsetAsync(cursor, 0, 50176 * 4, stream);
    count_int_kernel<<<(N_EDGES + 255) / 256, 256, 0, stream>>>(dst, degi, N_EDGES);
    scan1_kernel<<<196, 256, 0, stream>>>(degi, starts, bsum);
    scan2_kernel<<<1, 256, 0, stream>>>(bsum, boff, starts, 196);
    scan3_kernel<<<196, 256, 0, stream>>>(starts, boff);
    fill_csr_kernel<<<(N_EDGES + 255) / 256, 256, 0, stream>>>(src, dst, starts, cursor, csr);
    gstart_kernel<<<196, 256, 0, stream>>>(batch, gstart);
    cntinv_kernel<<<2, 256, 0, stream>>>(gstart, cntinv);

    // ---- conversions ----
    conv_x_kernel<<<(N_NODES * 64 + 255) / 256, 256, 0, stream>>>(x, abuf1);
    conv_w_kernel<50, 64, 128><<<(128 * 64 + 255) / 256, 256, 0, stream>>>(Wl1, Wr1, wb1);
    conv_w_kernel<128, 128, 256><<<(256 * 128 + 255) / 256, 256, 0, stream>>>(Wl2, Wr2, wb2);
    conv_w_kernel<256, 256, 512><<<(512 * 256 + 255) / 256, 256, 0, stream>>>(Wl3, Wr3, wb3);

    const int GB = 12500;
    const int MB = M_PAD / 128;   // 391

    // ---- layer 1: 50 -> 128, leaky_relu ----
    csr_agg_kernel<64><<<GB, 256, 0, stream>>>(starts, csr, abuf1);
    gemm_bf16_kernel<128, 1, 0, 0><<<MB * 1, 256, 0, stream>>>(
        abuf1, wb1, bl1, abuf2, 256, 128, nullptr, nullptr, N_NODES);

    // ---- layer 2: 128 -> 256, relu ----
    csr_agg_kernel<128><<<GB, 256, 0, stream>>>(starts, csr, abuf2);
    gemm_bf16_kernel<256, 2, 1, 0><<<MB * 2, 256, 0, stream>>>(
        abuf2, wb2, bl2, abuf3, 512, 256, nullptr, nullptr, N_NODES);

    // ---- layer 3: 256 -> 512, relu + fused pool sum ----
    csr_agg_kernel<256><<<GB, 256, 0, stream>>>(starts, csr, abuf3);
    hipMemsetAsync(pool, 0, (size_t)512 * 512 * 4, stream);
    gemm_bf16_kernel<512, 4, 1, 1><<<MB * 4, 256, 0, stream>>>(
        abuf3, wb3, bl3, nullptr, 0, 0, pool, batch, N_NODES);

    // ---- MLP head (fp32) ----
    dense_small_kernel<512, 256, 1><<<N_GRAPHS, 256, 0, stream>>>(pool, Wf1, bf1, cntinv, x4);
    dense_small_kernel<256, 128, 1><<<N_GRAPHS, 128, 0, stream>>>(x4, Wf2, bf2, nullptr, x5);
    dense_small_kernel<128, 1, 2><<<N_GRAPHS, 64, 0, stream>>>(x5, Wo, bo, nullptr, (float*)d_out);
}